// Round 3
// baseline (1034.910 us; speedup 1.0000x reference)
//
#include <hip/hip_runtime.h>
#include <cmath>

// Problem constants
#define BB 2
#define SS 2048
#define DD 2048
#define HH 16
#define HDIM 128
#define DFF 8192
#define MROWS 4096  // B*S

typedef unsigned short u16;
typedef unsigned int u32;
typedef short short8 __attribute__((ext_vector_type(8)));
typedef u16 u16x8 __attribute__((ext_vector_type(8)));
typedef float f32x4 __attribute__((ext_vector_type(4)));
typedef float f4 __attribute__((ext_vector_type(4)));

__device__ __forceinline__ u16 f2bf(float f) {
  u32 u = __float_as_uint(f);
  u = (u + 0x7fffu + ((u >> 16) & 1u)) >> 16;
  return (u16)u;
}

__device__ __forceinline__ f32x4 mfma16(short8 a, short8 b, f32x4 c) {
  return __builtin_amdgcn_mfma_f32_16x16x32_bf16(a, b, c, 0, 0, 0);
}

// async global->LDS, 16B per lane. LDS dest must be wave-uniform base + lane*16,
// but the GLOBAL address is per-lane -> we can swizzle on the producer side.
__device__ __forceinline__ void gload16(const void* g, void* l) {
  __builtin_amdgcn_global_load_lds((const __attribute__((address_space(1))) u32*)g,
                                   (__attribute__((address_space(3))) u32*)l, 16, 0, 0);
}

// ---------------- weight transpose + bf16 convert: Wt[n][k] = bf16(W[k][n]) -----
__global__ __launch_bounds__(256) void transpose_w(const float* __restrict__ W,
                                                   u16* __restrict__ Wt, int K, int N) {
  __shared__ float t[32][33];
  int n0 = blockIdx.x * 32, k0 = blockIdx.y * 32;
  int tx = threadIdx.x & 31, ty = threadIdx.x >> 5;  // ty in [0,8)
#pragma unroll
  for (int i = 0; i < 4; i++) t[ty + i * 8][tx] = W[(size_t)(k0 + ty + i * 8) * N + n0 + tx];
  __syncthreads();
#pragma unroll
  for (int i = 0; i < 4; i++)
    Wt[(size_t)(n0 + ty + i * 8) * K + k0 + tx] = f2bf(t[tx][ty + i * 8]);
}

// ---------------- key-padding bias: kb[i] = mask ? 0 : -1e30 ----------------
__global__ void prep_mask(const int* __restrict__ m, float* __restrict__ kb) {
  int i = blockIdx.x * 256 + threadIdx.x;
  kb[i] = m[i] ? 0.f : -1e30f;
}

// ---------------- layernorm row kernel: fp32 in -> bf16 out ----------------
__global__ __launch_bounds__(256) void ln_bf16(const float* __restrict__ x,
                                               const float* __restrict__ g,
                                               const float* __restrict__ bta,
                                               u16* __restrict__ out) {
  int row = blockIdx.x;
  int t = threadIdx.x;
  const f4* xr = (const f4*)(x + (size_t)row * DD);
  f4 a = xr[t * 2], c = xr[t * 2 + 1];
  float s = a[0] + a[1] + a[2] + a[3] + c[0] + c[1] + c[2] + c[3];
  float q = a[0]*a[0] + a[1]*a[1] + a[2]*a[2] + a[3]*a[3]
          + c[0]*c[0] + c[1]*c[1] + c[2]*c[2] + c[3]*c[3];
#pragma unroll
  for (int off = 32; off >= 1; off >>= 1) {
    s += __shfl_down(s, off);
    q += __shfl_down(q, off);
  }
  __shared__ float red[8];
  int wv = t >> 6;
  if ((t & 63) == 0) { red[wv] = s; red[4 + wv] = q; }
  __syncthreads();
  s = red[0] + red[1] + red[2] + red[3];
  q = red[4] + red[5] + red[6] + red[7];
  float mu = s * (1.f / DD);
  float rstd = rsqrtf(q * (1.f / DD) - mu * mu + 1e-5f);
  const f4* gp = (const f4*)g;
  const f4* bp = (const f4*)bta;
  f4 g0 = gp[t * 2], g1 = gp[t * 2 + 1], b0 = bp[t * 2], b1 = bp[t * 2 + 1];
  u16x8 r8;
  r8[0] = f2bf((a[0] - mu) * rstd * g0[0] + b0[0]);
  r8[1] = f2bf((a[1] - mu) * rstd * g0[1] + b0[1]);
  r8[2] = f2bf((a[2] - mu) * rstd * g0[2] + b0[2]);
  r8[3] = f2bf((a[3] - mu) * rstd * g0[3] + b0[3]);
  r8[4] = f2bf((c[0] - mu) * rstd * g1[0] + b1[0]);
  r8[5] = f2bf((c[1] - mu) * rstd * g1[1] + b1[1]);
  r8[6] = f2bf((c[2] - mu) * rstd * g1[2] + b1[2]);
  r8[7] = f2bf((c[3] - mu) * rstd * g1[3] + b1[3]);
  *(u16x8*)(out + (size_t)row * DD + t * 8) = r8;
}

// ---------------- generic bf16 GEMM: C = A[M,K] @ Wt[N,K]^T, m97 recipe --------
// EPI 2: out fp32 [M,N] = acc + bias + resid
// EPI 3: out bf16 [M,N] = gelu_exact(acc + bias)
// EPI 4: fused QKV: N=6144; col<2048 -> Q*scale [B,H,S,HD]; <4096 -> K [B,H,S,HD];
//        else V^T [B,H,HD,S]. Out regions contiguous at outp (+8388608 u16 each).
template <int EPI>
__global__ __launch_bounds__(256) void gemm_bt(const u16* __restrict__ A,
                                               const u16* __restrict__ Bt,
                                               const float* __restrict__ bias,
                                               const float* __restrict__ bias2,
                                               const float* __restrict__ bias3,
                                               const float* __restrict__ resid,
                                               void* __restrict__ outp,
                                               int M, int N, int K, float scale) {
  __shared__ u16 As[128 * 32];
  __shared__ u16 Bs[128 * 32];
  int tid = threadIdx.x, w = tid >> 6, lane = tid & 63, ln = lane & 15, quad = lane >> 4;
  int n0 = blockIdx.x * 128, m0 = blockIdx.y * 128;
  int wm = (w & 1) * 64, wn = (w >> 1) * 64;
  f32x4 acc[4][4] = {};
  const u16* ap = A + (size_t)m0 * K;
  const u16* bp = Bt + (size_t)n0 * K;
  int nkt = K >> 5;
  for (int kt = 0; kt < nkt; kt++) {
    int k0 = kt * 32;
#pragma unroll
    for (int i = 0; i < 2; i++) {
      int c = i * 256 + tid, row = c >> 2, cc = c & 3;
      gload16(ap + (size_t)row * K + k0 + cc * 8, &As[c * 8]);
    }
#pragma unroll
    for (int i = 0; i < 2; i++) {
      int c = i * 256 + tid, row = c >> 2, cc = c & 3;
      gload16(bp + (size_t)row * K + k0 + cc * 8, &Bs[c * 8]);
    }
    __syncthreads();
    short8 af[4], bf[4];
#pragma unroll
    for (int i = 0; i < 4; i++) af[i] = *(const short8*)&As[(wm + i * 16 + ln) * 32 + quad * 8];
#pragma unroll
    for (int j = 0; j < 4; j++) bf[j] = *(const short8*)&Bs[(wn + j * 16 + ln) * 32 + quad * 8];
#pragma unroll
    for (int i = 0; i < 4; i++)
#pragma unroll
      for (int j = 0; j < 4; j++) acc[i][j] = mfma16(af[i], bf[j], acc[i][j]);
    __syncthreads();
  }
  // epilogue
#pragma unroll
  for (int i = 0; i < 4; i++) {
    int row = m0 + wm + i * 16 + quad * 4;
#pragma unroll
    for (int j = 0; j < 4; j++) {
      int col = n0 + wn + j * 16 + ln;
      float bvv;
      int qkv = 0, dcol = col;
      if (EPI == 4) {
        qkv = col >> 11;
        dcol = col & 2047;
        bvv = (qkv == 0 ? bias : qkv == 1 ? bias2 : bias3)[dcol];
      } else {
        bvv = bias[col];
      }
#pragma unroll
      for (int r = 0; r < 4; r++) {
        float v = acc[i][j][r] + bvv;
        int rw = row + r;
        if (EPI == 2) {
          v += resid[(size_t)rw * N + col];
          ((float*)outp)[(size_t)rw * N + col] = v;
        } else if (EPI == 3) {
          float gv = 0.5f * v * (1.0f + erff(v * 0.70710678118654752f));
          ((u16*)outp)[(size_t)rw * N + col] = f2bf(gv);
        } else {
          int b_ = rw >> 11, s_ = rw & 2047, hh = dcol >> 7, hd = dcol & 127;
          u16* o16 = (u16*)outp;
          if (qkv == 0) {
            o16[(((size_t)(b_ * HH + hh) * SS + s_) << 7) + hd] = f2bf(v * scale);
          } else if (qkv == 1) {
            o16[8388608 + (((size_t)(b_ * HH + hh) * SS + s_) << 7) + hd] = f2bf(v);
          } else {
            o16[16777216 + (((size_t)(b_ * HH + hh) * HDIM + hd) << 11) + s_] = f2bf(v);
          }
        }
      }
    }
  }
}

// ---------------- split-K GEMM: P[z] = A[:, z*klen:(z+1)*klen] @ Bt^T ----------
// Writes raw fp32 partial tile (no bias). P has M*N floats per slice.
__global__ __launch_bounds__(256) void gemm_bt_splitk(const u16* __restrict__ A,
                                                      const u16* __restrict__ Bt,
                                                      float* __restrict__ P,
                                                      int M, int N, int K, int klen) {
  __shared__ u16 As[128 * 32];
  __shared__ u16 Bs[128 * 32];
  int tid = threadIdx.x, w = tid >> 6, lane = tid & 63, ln = lane & 15, quad = lane >> 4;
  int n0 = blockIdx.x * 128, m0 = blockIdx.y * 128, z = blockIdx.z;
  int kbeg = z * klen;
  int wm = (w & 1) * 64, wn = (w >> 1) * 64;
  f32x4 acc[4][4] = {};
  const u16* ap = A + (size_t)m0 * K + kbeg;
  const u16* bp = Bt + (size_t)n0 * K + kbeg;
  float* Pz = P + (size_t)z * M * N;
  int nkt = klen >> 5;
  for (int kt = 0; kt < nkt; kt++) {
    int k0 = kt * 32;
#pragma unroll
    for (int i = 0; i < 2; i++) {
      int c = i * 256 + tid, row = c >> 2, cc = c & 3;
      gload16(ap + (size_t)row * K + k0 + cc * 8, &As[c * 8]);
    }
#pragma unroll
    for (int i = 0; i < 2; i++) {
      int c = i * 256 + tid, row = c >> 2, cc = c & 3;
      gload16(bp + (size_t)row * K + k0 + cc * 8, &Bs[c * 8]);
    }
    __syncthreads();
    short8 af[4], bf[4];
#pragma unroll
    for (int i = 0; i < 4; i++) af[i] = *(const short8*)&As[(wm + i * 16 + ln) * 32 + quad * 8];
#pragma unroll
    for (int j = 0; j < 4; j++) bf[j] = *(const short8*)&Bs[(wn + j * 16 + ln) * 32 + quad * 8];
#pragma unroll
    for (int i = 0; i < 4; i++)
#pragma unroll
      for (int j = 0; j < 4; j++) acc[i][j] = mfma16(af[i], bf[j], acc[i][j]);
    __syncthreads();
  }
#pragma unroll
  for (int i = 0; i < 4; i++) {
    int row = m0 + wm + i * 16 + quad * 4;
#pragma unroll
    for (int j = 0; j < 4; j++) {
      int col = n0 + wn + j * 16 + ln;
#pragma unroll
      for (int r = 0; r < 4; r++) Pz[(size_t)(row + r) * N + col] = acc[i][j][r];
    }
  }
}

// ---------------- split-K fixup: out = p0 + p1 + bias[col] + resid ------------
__global__ __launch_bounds__(256) void splitk_fix(const float* __restrict__ P0,
                                                  const float* __restrict__ P1,
                                                  const float* __restrict__ bias,
                                                  const float* __restrict__ resid,
                                                  float* __restrict__ out) {
  int i = blockIdx.x * 1024 + threadIdx.x * 4;
  f4 a = *(const f4*)(P0 + i);
  f4 b = *(const f4*)(P1 + i);
  f4 rr = *(const f4*)(resid + i);
  f4 bb = *(const f4*)(bias + (i & 2047));
  f4 o = a + b + rr + bb;
  *(f4*)(out + i) = o;
}

// ---------------- flash attention v2 --------------------------------------
// Q pre-scaled by 1/sqrt(HD) at QKV epilogue. Causal + key-pad bias.
// Q,K: bf16 [B*H, S, HD]; Vt: bf16 [B*H, HD, S]; out: bf16 [B, S, H*HD]
// - paired Q-tiles (qt, 31-qt): every block does exactly 33 K-tile iterations
// - XOR chunk-swizzled LDS (16B granularity) -> conflict-free b128 reads
// - double-buffered K/V staging, prefetch issued right after the top barrier
__global__ __launch_bounds__(256) void attn_kernel(const u16* __restrict__ Q,
                                                   const u16* __restrict__ Kg,
                                                   const u16* __restrict__ Vtg,
                                                   const float* __restrict__ kb,
                                                   u16* __restrict__ Out) {
  __shared__ u16 Ks[2][64 * 128];  // logical [sk][hd], chunk-swizzled
  __shared__ u16 Vs[2][128 * 64];  // logical [hd][sk], chunk-swizzled
  __shared__ u16 Ps[64 * 64];      // logical [q][sk], chunk-swizzled, per-wave rows
  int tid = threadIdx.x, w = tid >> 6, lane = tid & 63, ln = lane & 15, quad = lane >> 4;
  int bh = blockIdx.y, b = bh >> 4;
  const u16* kgB = Kg + (size_t)bh * SS * HDIM;
  const u16* vgB = Vtg + (size_t)bh * HDIM * SS;

  auto stage = [&](int buf, int kt) {
    const u16* kg = kgB + (size_t)kt * 64 * HDIM;
#pragma unroll
    for (int i = 0; i < 4; i++) {
      int c = i * 256 + tid, r = c >> 4;
      int jl = (c & 15) ^ (r & 7);
      gload16(kg + r * HDIM + jl * 8, &Ks[buf][c * 8]);
    }
    const u16* vg = vgB + kt * 64;
#pragma unroll
    for (int i = 0; i < 4; i++) {
      int c = i * 256 + tid, r = c >> 3;
      int jl = (c & 7) ^ (r & 7);
      gload16(vg + (size_t)r * SS + jl * 8, &Vs[buf][c * 8]);
    }
  };

#pragma unroll 1
  for (int half = 0; half < 2; half++) {
    int qt = half ? (31 - blockIdx.x) : blockIdx.x;
    int q0 = qt * 64;
    short8 qf[4];
    size_t qbase = ((size_t)bh * SS + q0 + w * 16 + ln) * HDIM;
#pragma unroll
    for (int ks = 0; ks < 4; ks++) qf[ks] = *(const short8*)(Q + qbase + ks * 32 + quad * 8);
    f32x4 o[8] = {};
    float mrow[4], lrow[4];
#pragma unroll
    for (int r = 0; r < 4; r++) { mrow[r] = -1e30f; lrow[r] = 0.f; }
    int nkt = qt + 1;
    __syncthreads();  // prior half's LDS reads complete before restaging
    stage(0, 0);
    int cur = 0;
    for (int kt = 0; kt < nkt; kt++) {
      __syncthreads();  // drains loads staged one iteration ago
      if (kt + 1 < nkt) stage(cur ^ 1, kt + 1);
      const u16* KsB = Ks[cur];
      const u16* VsB = Vs[cur];
      float kbv[4];
#pragma unroll
      for (int nt = 0; nt < 4; nt++) kbv[nt] = kb[b * SS + kt * 64 + nt * 16 + ln];
      // S = Q K^T
      f32x4 sc[4] = {};
#pragma unroll
      for (int ks = 0; ks < 4; ks++)
#pragma unroll
        for (int nt = 0; nt < 4; nt++) {
          short8 kf = *(const short8*)&KsB[(nt * 16 + ln) * 128 +
                                           (((ks * 4 + quad) ^ (ln & 7)) << 3)];
          sc[nt] = mfma16(qf[ks], kf, sc[nt]);
        }
      // online softmax
      bool diag = (kt == nkt - 1);
      int rowg = q0 + w * 16 + quad * 4;
      float mt[4] = {-3e30f, -3e30f, -3e30f, -3e30f};
#pragma unroll
      for (int nt = 0; nt < 4; nt++) {
        int colg = kt * 64 + nt * 16 + ln;
#pragma unroll
        for (int r = 0; r < 4; r++) {
          float s = sc[nt][r] + kbv[nt];
          if (diag && colg > rowg + r) s = -3e30f;
          sc[nt][r] = s;
          mt[r] = fmaxf(mt[r], s);
        }
      }
#pragma unroll
      for (int off = 8; off >= 1; off >>= 1)
#pragma unroll
        for (int r = 0; r < 4; r++) mt[r] = fmaxf(mt[r], __shfl_xor(mt[r], off, 16));
      float al[4], lt[4];
#pragma unroll
      for (int r = 0; r < 4; r++) {
        float mn = fmaxf(mrow[r], mt[r]);
        al[r] = __expf(mrow[r] - mn);
        mrow[r] = mn;
        lt[r] = 0.f;
      }
#pragma unroll
      for (int nt = 0; nt < 4; nt++)
#pragma unroll
        for (int r = 0; r < 4; r++) {
          float e = __expf(sc[nt][r] - mrow[r]);
          sc[nt][r] = e;
          lt[r] += e;
        }
#pragma unroll
      for (int off = 8; off >= 1; off >>= 1)
#pragma unroll
        for (int r = 0; r < 4; r++) lt[r] += __shfl_xor(lt[r], off, 16);
#pragma unroll
      for (int r = 0; r < 4; r++) lrow[r] = lrow[r] * al[r] + lt[r];
#pragma unroll
      for (int h8 = 0; h8 < 8; h8++)
#pragma unroll
        for (int r = 0; r < 4; r++) o[h8][r] *= al[r];
      // P: C-layout -> LDS (swizzled) -> A-layout; per-wave rows, DS in-order
#pragma unroll
      for (int nt = 0; nt < 4; nt++)
#pragma unroll
        for (int r = 0; r < 4; r++) {
          int prow = w * 16 + quad * 4 + r;
          int pcol = nt * 16 + ln;
          Ps[prow * 64 + (((pcol >> 3) ^ (prow & 7)) << 3) + (pcol & 7)] = f2bf(sc[nt][r]);
        }
#pragma unroll
      for (int ks2 = 0; ks2 < 2; ks2++) {
        int sw = ((ks2 * 4 + quad) ^ (ln & 7)) << 3;
        short8 pf = *(const short8*)&Ps[(w * 16 + ln) * 64 + sw];
#pragma unroll
        for (int h8 = 0; h8 < 8; h8++) {
          short8 vf = *(const short8*)&VsB[(h8 * 16 + ln) * 64 + sw];
          o[h8] = mfma16(pf, vf, o[h8]);
        }
      }
      cur ^= 1;
    }
    // epilogue: divide by l, write [B,S,H*HD] bf16
    float inv[4];
#pragma unroll
    for (int r = 0; r < 4; r++) inv[r] = 1.0f / lrow[r];
    int srow = q0 + w * 16 + quad * 4;
#pragma unroll
    for (int h8 = 0; h8 < 8; h8++) {
      int col = h8 * 16 + ln;
#pragma unroll
      for (int r = 0; r < 4; r++) {
        size_t idx = ((size_t)b * SS + srow + r) * DD + (size_t)(bh & 15) * HDIM + col;
        Out[idx] = f2bf(o[h8][r] * inv[r]);
      }
    }
  }
}

extern "C" void kernel_launch(void* const* d_in, const int* in_sizes, int n_in,
                              void* d_out, int out_size, void* d_ws, size_t ws_size,
                              hipStream_t stream) {
  const float* x    = (const float*)d_in[0];
  const int*   amask= (const int*)d_in[1];
  const float* ln1g = (const float*)d_in[2];
  const float* ln1b = (const float*)d_in[3];
  const float* wq   = (const float*)d_in[4];
  const float* bq   = (const float*)d_in[5];
  const float* wk   = (const float*)d_in[6];
  const float* bk   = (const float*)d_in[7];
  const float* wv   = (const float*)d_in[8];
  const float* bv   = (const float*)d_in[9];
  const float* wo   = (const float*)d_in[10];
  const float* bo   = (const float*)d_in[11];
  const float* ln2g = (const float*)d_in[12];
  const float* ln2b = (const float*)d_in[13];
  const float* w1   = (const float*)d_in[14];
  const float* b1   = (const float*)d_in[15];
  const float* w2   = (const float*)d_in[16];
  const float* b2   = (const float*)d_in[17];

  char* ws = (char*)d_ws;
  u16* wqT  = (u16*)(ws + 0);          // 8.39 MB each (2048x2048 bf16)
  u16* wkT  = (u16*)(ws + 8388608);    // contiguous with wqT -> fused [6144][2048]
  u16* wvT  = (u16*)(ws + 16777216);
  u16* woT  = (u16*)(ws + 25165824);
  u16* w1T  = (u16*)(ws + 33554432);   // 33.55 MB (8192x2048)
  u16* w2T  = (u16*)(ws + 67108864);   // 33.55 MB (2048x8192)
  u16* hbuf = (u16*)(ws + 100663296);  // 16.78 MB; reused for h2
  u16* qbuf = (u16*)(ws + 117440512);  // 16.78 MB  (K at +8388608 u16, Vt at +16777216 u16)
  u16* kbuf = (u16*)(ws + 134217728);
  u16* vtb  = (u16*)(ws + 150994944);
  u16* atb  = (u16*)(ws + 167772160);  // 16.78 MB
  float* x2 = (float*)(ws + 184549376);// 33.55 MB fp32
  float* kb = (float*)(ws + 218103808);// 16 KB
  u16* ff1  = qbuf;                    // overlays qbuf..atb (exactly 67.1 MB)
  // split-K partials for FFN2: overlay wqT..woT (dead) and w1T (dead by then).
  // 2 slices x 4096x2048 fp32 = 2 x 33.55 MB at ws+0.
  float* pbuf = (float*)(ws + 0);

  // weight prep (fp32 -> bf16, transposed)
  transpose_w<<<dim3(64, 64), 256, 0, stream>>>(wq, wqT, 2048, 2048);
  transpose_w<<<dim3(64, 64), 256, 0, stream>>>(wk, wkT, 2048, 2048);
  transpose_w<<<dim3(64, 64), 256, 0, stream>>>(wv, wvT, 2048, 2048);
  transpose_w<<<dim3(64, 64), 256, 0, stream>>>(wo, woT, 2048, 2048);
  transpose_w<<<dim3(256, 64), 256, 0, stream>>>(w1, w1T, 2048, 8192);
  transpose_w<<<dim3(64, 256), 256, 0, stream>>>(w2, w2T, 8192, 2048);
  prep_mask<<<16, 256, 0, stream>>>(amask, kb);

  // attention path
  ln_bf16<<<4096, 256, 0, stream>>>(x, ln1g, ln1b, hbuf);
  const float qscale = 0.08838834764831845f;  // 1/sqrt(128)
  // fused QKV: Bt = [wqT|wkT|wvT] contiguous, N=6144
  gemm_bt<4><<<dim3(48, 32), 256, 0, stream>>>(hbuf, wqT, bq, bk, bv, nullptr, qbuf,
                                               4096, 6144, 2048, qscale);
  attn_kernel<<<dim3(16, 32), 256, 0, stream>>>(qbuf, kbuf, vtb, kb, atb);
  gemm_bt<2><<<dim3(16, 32), 256, 0, stream>>>(atb, woT, bo, nullptr, nullptr, x, x2,
                                               4096, 2048, 2048, 1.0f);

  // FFN path
  ln_bf16<<<4096, 256, 0, stream>>>(x2, ln2g, ln2b, hbuf);
  gemm_bt<3><<<dim3(64, 32), 256, 0, stream>>>(hbuf, w1T, b1, nullptr, nullptr, nullptr, ff1,
                                               4096, 8192, 2048, 1.0f);
  // FFN2 via split-K=2 (occupancy fix: 512 -> 1024 blocks)
  gemm_bt_splitk<<<dim3(16, 32, 2), 256, 0, stream>>>(ff1, w2T, pbuf, 4096, 2048, 8192, 4096);
  splitk_fix<<<8192, 256, 0, stream>>>(pbuf, pbuf + (size_t)4096 * 2048, b2, x2,
                                       (float*)d_out);
}

// Round 4
// 937.868 us; speedup vs baseline: 1.1035x; 1.1035x over previous
//
#include <hip/hip_runtime.h>
#include <cmath>

// Problem constants
#define BB 2
#define SS 2048
#define DD 2048
#define HH 16
#define HDIM 128
#define DFF 8192
#define MROWS 4096  // B*S

typedef unsigned short u16;
typedef unsigned int u32;
typedef short short8 __attribute__((ext_vector_type(8)));
typedef u16 u16x8 __attribute__((ext_vector_type(8)));
typedef float f32x4 __attribute__((ext_vector_type(4)));
typedef float f4 __attribute__((ext_vector_type(4)));

__device__ __forceinline__ u16 f2bf(float f) {
  u32 u = __float_as_uint(f);
  u = (u + 0x7fffu + ((u >> 16) & 1u)) >> 16;
  return (u16)u;
}

__device__ __forceinline__ f32x4 mfma16(short8 a, short8 b, f32x4 c) {
  return __builtin_amdgcn_mfma_f32_16x16x32_bf16(a, b, c, 0, 0, 0);
}

// async global->LDS, 16B per lane. LDS dest must be wave-uniform base + lane*16,
// but the GLOBAL address is per-lane -> we can swizzle on the producer side.
__device__ __forceinline__ void gload16(const void* g, void* l) {
  __builtin_amdgcn_global_load_lds((const __attribute__((address_space(1))) u32*)g,
                                   (__attribute__((address_space(3))) u32*)l, 16, 0, 0);
}

// ---------------- weight transpose + bf16 convert: Wt[n][k] = bf16(W[k][n]) -----
__global__ __launch_bounds__(256) void transpose_w(const float* __restrict__ W,
                                                   u16* __restrict__ Wt, int K, int N) {
  __shared__ float t[32][33];
  int n0 = blockIdx.x * 32, k0 = blockIdx.y * 32;
  int tx = threadIdx.x & 31, ty = threadIdx.x >> 5;  // ty in [0,8)
#pragma unroll
  for (int i = 0; i < 4; i++) t[ty + i * 8][tx] = W[(size_t)(k0 + ty + i * 8) * N + n0 + tx];
  __syncthreads();
#pragma unroll
  for (int i = 0; i < 4; i++)
    Wt[(size_t)(n0 + ty + i * 8) * K + k0 + tx] = f2bf(t[tx][ty + i * 8]);
}

// ---------------- key-padding bias: kb[i] = mask ? 0 : -1e30 ----------------
__global__ void prep_mask(const int* __restrict__ m, float* __restrict__ kb) {
  int i = blockIdx.x * 256 + threadIdx.x;
  kb[i] = m[i] ? 0.f : -1e30f;
}

// ---------------- layernorm row kernel: fp32 in -> bf16 out ----------------
__global__ __launch_bounds__(256) void ln_bf16(const float* __restrict__ x,
                                               const float* __restrict__ g,
                                               const float* __restrict__ bta,
                                               u16* __restrict__ out) {
  int row = blockIdx.x;
  int t = threadIdx.x;
  const f4* xr = (const f4*)(x + (size_t)row * DD);
  f4 a = xr[t * 2], c = xr[t * 2 + 1];
  float s = a[0] + a[1] + a[2] + a[3] + c[0] + c[1] + c[2] + c[3];
  float q = a[0]*a[0] + a[1]*a[1] + a[2]*a[2] + a[3]*a[3]
          + c[0]*c[0] + c[1]*c[1] + c[2]*c[2] + c[3]*c[3];
#pragma unroll
  for (int off = 32; off >= 1; off >>= 1) {
    s += __shfl_down(s, off);
    q += __shfl_down(q, off);
  }
  __shared__ float red[8];
  int wv = t >> 6;
  if ((t & 63) == 0) { red[wv] = s; red[4 + wv] = q; }
  __syncthreads();
  s = red[0] + red[1] + red[2] + red[3];
  q = red[4] + red[5] + red[6] + red[7];
  float mu = s * (1.f / DD);
  float rstd = rsqrtf(q * (1.f / DD) - mu * mu + 1e-5f);
  const f4* gp = (const f4*)g;
  const f4* bp = (const f4*)bta;
  f4 g0 = gp[t * 2], g1 = gp[t * 2 + 1], b0 = bp[t * 2], b1 = bp[t * 2 + 1];
  u16x8 r8;
  r8[0] = f2bf((a[0] - mu) * rstd * g0[0] + b0[0]);
  r8[1] = f2bf((a[1] - mu) * rstd * g0[1] + b0[1]);
  r8[2] = f2bf((a[2] - mu) * rstd * g0[2] + b0[2]);
  r8[3] = f2bf((a[3] - mu) * rstd * g0[3] + b0[3]);
  r8[4] = f2bf((c[0] - mu) * rstd * g1[0] + b1[0]);
  r8[5] = f2bf((c[1] - mu) * rstd * g1[1] + b1[1]);
  r8[6] = f2bf((c[2] - mu) * rstd * g1[2] + b1[2]);
  r8[7] = f2bf((c[3] - mu) * rstd * g1[3] + b1[7-4]);
  *(u16x8*)(out + (size_t)row * DD + t * 8) = r8;
}

// ---------------- generic bf16 GEMM: C = A[M,K] @ Wt[N,K]^T, m97 recipe --------
// __launch_bounds__(256,4): cap total regs/wave (VGPR+AGPR unified) at 128 so
// 4 blocks/CU are resident (R3 post-mortem: 132/164 total regs -> 2 blocks/CU
// -> latency-bound at 25% MfmaUtil; occupancy was register-, not grid-limited).
// EPI 2: out fp32 [M,N] = acc + bias + resid
// EPI 3: out bf16 [M,N] = gelu_exact(acc + bias)
// EPI 4: fused QKV: N=6144; col<2048 -> Q*scale [B,H,S,HD]; <4096 -> K [B,H,S,HD];
//        else V^T [B,H,HD,S]. Out regions contiguous at outp (+8388608 u16 each).
template <int EPI>
__global__ __launch_bounds__(256, 4) void gemm_bt(const u16* __restrict__ A,
                                               const u16* __restrict__ Bt,
                                               const float* __restrict__ bias,
                                               const float* __restrict__ bias2,
                                               const float* __restrict__ bias3,
                                               const float* __restrict__ resid,
                                               void* __restrict__ outp,
                                               int M, int N, int K, float scale) {
  __shared__ u16 As[128 * 32];
  __shared__ u16 Bs[128 * 32];
  int tid = threadIdx.x, w = tid >> 6, lane = tid & 63, ln = lane & 15, quad = lane >> 4;
  int n0 = blockIdx.x * 128, m0 = blockIdx.y * 128;
  int wm = (w & 1) * 64, wn = (w >> 1) * 64;
  f32x4 acc[4][4] = {};
  const u16* ap = A + (size_t)m0 * K;
  const u16* bp = Bt + (size_t)n0 * K;
  int nkt = K >> 5;
  for (int kt = 0; kt < nkt; kt++) {
    int k0 = kt * 32;
#pragma unroll
    for (int i = 0; i < 2; i++) {
      int c = i * 256 + tid, row = c >> 2, cc = c & 3;
      gload16(ap + (size_t)row * K + k0 + cc * 8, &As[c * 8]);
    }
#pragma unroll
    for (int i = 0; i < 2; i++) {
      int c = i * 256 + tid, row = c >> 2, cc = c & 3;
      gload16(bp + (size_t)row * K + k0 + cc * 8, &Bs[c * 8]);
    }
    __syncthreads();
    short8 af[4], bf[4];
#pragma unroll
    for (int i = 0; i < 4; i++) af[i] = *(const short8*)&As[(wm + i * 16 + ln) * 32 + quad * 8];
#pragma unroll
    for (int j = 0; j < 4; j++) bf[j] = *(const short8*)&Bs[(wn + j * 16 + ln) * 32 + quad * 8];
#pragma unroll
    for (int i = 0; i < 4; i++)
#pragma unroll
      for (int j = 0; j < 4; j++) acc[i][j] = mfma16(af[i], bf[j], acc[i][j]);
    __syncthreads();
  }
  // epilogue
#pragma unroll
  for (int i = 0; i < 4; i++) {
    int row = m0 + wm + i * 16 + quad * 4;
#pragma unroll
    for (int j = 0; j < 4; j++) {
      int col = n0 + wn + j * 16 + ln;
      float bvv;
      int qkv = 0, dcol = col;
      if (EPI == 4) {
        qkv = col >> 11;
        dcol = col & 2047;
        bvv = (qkv == 0 ? bias : qkv == 1 ? bias2 : bias3)[dcol];
      } else {
        bvv = bias[col];
      }
#pragma unroll
      for (int r = 0; r < 4; r++) {
        float v = acc[i][j][r] + bvv;
        int rw = row + r;
        if (EPI == 2) {
          v += resid[(size_t)rw * N + col];
          ((float*)outp)[(size_t)rw * N + col] = v;
        } else if (EPI == 3) {
          float gv = 0.5f * v * (1.0f + erff(v * 0.70710678118654752f));
          ((u16*)outp)[(size_t)rw * N + col] = f2bf(gv);
        } else {
          int b_ = rw >> 11, s_ = rw & 2047, hh = dcol >> 7, hd = dcol & 127;
          u16* o16 = (u16*)outp;
          if (qkv == 0) {
            o16[(((size_t)(b_ * HH + hh) * SS + s_) << 7) + hd] = f2bf(v * scale);
          } else if (qkv == 1) {
            o16[8388608 + (((size_t)(b_ * HH + hh) * SS + s_) << 7) + hd] = f2bf(v);
          } else {
            o16[16777216 + (((size_t)(b_ * HH + hh) * HDIM + hd) << 11) + s_] = f2bf(v);
          }
        }
      }
    }
  }
}

// ---------------- split-K GEMM: P[z] = A[:, z*klen:(z+1)*klen] @ Bt^T ----------
// Writes raw fp32 partial tile (no bias). P has M*N floats per slice.
__global__ __launch_bounds__(256, 4) void gemm_bt_splitk(const u16* __restrict__ A,
                                                      const u16* __restrict__ Bt,
                                                      float* __restrict__ P,
                                                      int M, int N, int K, int klen) {
  __shared__ u16 As[128 * 32];
  __shared__ u16 Bs[128 * 32];
  int tid = threadIdx.x, w = tid >> 6, lane = tid & 63, ln = lane & 15, quad = lane >> 4;
  int n0 = blockIdx.x * 128, m0 = blockIdx.y * 128, z = blockIdx.z;
  int kbeg = z * klen;
  int wm = (w & 1) * 64, wn = (w >> 1) * 64;
  f32x4 acc[4][4] = {};
  const u16* ap = A + (size_t)m0 * K + kbeg;
  const u16* bp = Bt + (size_t)n0 * K + kbeg;
  float* Pz = P + (size_t)z * M * N;
  int nkt = klen >> 5;
  for (int kt = 0; kt < nkt; kt++) {
    int k0 = kt * 32;
#pragma unroll
    for (int i = 0; i < 2; i++) {
      int c = i * 256 + tid, row = c >> 2, cc = c & 3;
      gload16(ap + (size_t)row * K + k0 + cc * 8, &As[c * 8]);
    }
#pragma unroll
    for (int i = 0; i < 2; i++) {
      int c = i * 256 + tid, row = c >> 2, cc = c & 3;
      gload16(bp + (size_t)row * K + k0 + cc * 8, &Bs[c * 8]);
    }
    __syncthreads();
    short8 af[4], bf[4];
#pragma unroll
    for (int i = 0; i < 4; i++) af[i] = *(const short8*)&As[(wm + i * 16 + ln) * 32 + quad * 8];
#pragma unroll
    for (int j = 0; j < 4; j++) bf[j] = *(const short8*)&Bs[(wn + j * 16 + ln) * 32 + quad * 8];
#pragma unroll
    for (int i = 0; i < 4; i++)
#pragma unroll
      for (int j = 0; j < 4; j++) acc[i][j] = mfma16(af[i], bf[j], acc[i][j]);
    __syncthreads();
  }
#pragma unroll
  for (int i = 0; i < 4; i++) {
    int row = m0 + wm + i * 16 + quad * 4;
#pragma unroll
    for (int j = 0; j < 4; j++) {
      int col = n0 + wn + j * 16 + ln;
#pragma unroll
      for (int r = 0; r < 4; r++) Pz[(size_t)(row + r) * N + col] = acc[i][j][r];
    }
  }
}

// ---------------- split-K fixup: out = p0 + p1 + bias[col] + resid ------------
__global__ __launch_bounds__(256) void splitk_fix(const float* __restrict__ P0,
                                                  const float* __restrict__ P1,
                                                  const float* __restrict__ bias,
                                                  const float* __restrict__ resid,
                                                  float* __restrict__ out) {
  int i = blockIdx.x * 1024 + threadIdx.x * 4;
  f4 a = *(const f4*)(P0 + i);
  f4 b = *(const f4*)(P1 + i);
  f4 rr = *(const f4*)(resid + i);
  f4 bb = *(const f4*)(bias + (i & 2047));
  f4 o = a + b + rr + bb;
  *(f4*)(out + i) = o;
}

// ---------------- flash attention v2 --------------------------------------
// Q pre-scaled by 1/sqrt(HD) at QKV epilogue. Causal + key-pad bias.
// Q,K: bf16 [B*H, S, HD]; Vt: bf16 [B*H, HD, S]; out: bf16 [B, S, H*HD]
// - paired Q-tiles (qt, 31-qt): every block does exactly 33 K-tile iterations
// - XOR chunk-swizzled LDS (16B granularity) -> conflict-free b128 reads
// - double-buffered K/V staging, prefetch issued right after the top barrier
__global__ __launch_bounds__(256) void attn_kernel(const u16* __restrict__ Q,
                                                   const u16* __restrict__ Kg,
                                                   const u16* __restrict__ Vtg,
                                                   const float* __restrict__ kb,
                                                   u16* __restrict__ Out) {
  __shared__ u16 Ks[2][64 * 128];  // logical [sk][hd], chunk-swizzled
  __shared__ u16 Vs[2][128 * 64];  // logical [hd][sk], chunk-swizzled
  __shared__ u16 Ps[64 * 64];      // logical [q][sk], chunk-swizzled, per-wave rows
  int tid = threadIdx.x, w = tid >> 6, lane = tid & 63, ln = lane & 15, quad = lane >> 4;
  int bh = blockIdx.y, b = bh >> 4;
  const u16* kgB = Kg + (size_t)bh * SS * HDIM;
  const u16* vgB = Vtg + (size_t)bh * HDIM * SS;

  auto stage = [&](int buf, int kt) {
    const u16* kg = kgB + (size_t)kt * 64 * HDIM;
#pragma unroll
    for (int i = 0; i < 4; i++) {
      int c = i * 256 + tid, r = c >> 4;
      int jl = (c & 15) ^ (r & 7);
      gload16(kg + r * HDIM + jl * 8, &Ks[buf][c * 8]);
    }
    const u16* vg = vgB + kt * 64;
#pragma unroll
    for (int i = 0; i < 4; i++) {
      int c = i * 256 + tid, r = c >> 3;
      int jl = (c & 7) ^ (r & 7);
      gload16(vg + (size_t)r * SS + jl * 8, &Vs[buf][c * 8]);
    }
  };

#pragma unroll 1
  for (int half = 0; half < 2; half++) {
    int qt = half ? (31 - blockIdx.x) : blockIdx.x;
    int q0 = qt * 64;
    short8 qf[4];
    size_t qbase = ((size_t)bh * SS + q0 + w * 16 + ln) * HDIM;
#pragma unroll
    for (int ks = 0; ks < 4; ks++) qf[ks] = *(const short8*)(Q + qbase + ks * 32 + quad * 8);
    f32x4 o[8] = {};
    float mrow[4], lrow[4];
#pragma unroll
    for (int r = 0; r < 4; r++) { mrow[r] = -1e30f; lrow[r] = 0.f; }
    int nkt = qt + 1;
    __syncthreads();  // prior half's LDS reads complete before restaging
    stage(0, 0);
    int cur = 0;
    for (int kt = 0; kt < nkt; kt++) {
      __syncthreads();  // drains loads staged one iteration ago
      if (kt + 1 < nkt) stage(cur ^ 1, kt + 1);
      const u16* KsB = Ks[cur];
      const u16* VsB = Vs[cur];
      float kbv[4];
#pragma unroll
      for (int nt = 0; nt < 4; nt++) kbv[nt] = kb[b * SS + kt * 64 + nt * 16 + ln];
      // S = Q K^T
      f32x4 sc[4] = {};
#pragma unroll
      for (int ks = 0; ks < 4; ks++)
#pragma unroll
        for (int nt = 0; nt < 4; nt++) {
          short8 kf = *(const short8*)&KsB[(nt * 16 + ln) * 128 +
                                           (((ks * 4 + quad) ^ (ln & 7)) << 3)];
          sc[nt] = mfma16(qf[ks], kf, sc[nt]);
        }
      // online softmax
      bool diag = (kt == nkt - 1);
      int rowg = q0 + w * 16 + quad * 4;
      float mt[4] = {-3e30f, -3e30f, -3e30f, -3e30f};
#pragma unroll
      for (int nt = 0; nt < 4; nt++) {
        int colg = kt * 64 + nt * 16 + ln;
#pragma unroll
        for (int r = 0; r < 4; r++) {
          float s = sc[nt][r] + kbv[nt];
          if (diag && colg > rowg + r) s = -3e30f;
          sc[nt][r] = s;
          mt[r] = fmaxf(mt[r], s);
        }
      }
#pragma unroll
      for (int off = 8; off >= 1; off >>= 1)
#pragma unroll
        for (int r = 0; r < 4; r++) mt[r] = fmaxf(mt[r], __shfl_xor(mt[r], off, 16));
      float al[4], lt[4];
#pragma unroll
      for (int r = 0; r < 4; r++) {
        float mn = fmaxf(mrow[r], mt[r]);
        al[r] = __expf(mrow[r] - mn);
        mrow[r] = mn;
        lt[r] = 0.f;
      }
#pragma unroll
      for (int nt = 0; nt < 4; nt++)
#pragma unroll
        for (int r = 0; r < 4; r++) {
          float e = __expf(sc[nt][r] - mrow[r]);
          sc[nt][r] = e;
          lt[r] += e;
        }
#pragma unroll
      for (int off = 8; off >= 1; off >>= 1)
#pragma unroll
        for (int r = 0; r < 4; r++) lt[r] += __shfl_xor(lt[r], off, 16);
#pragma unroll
      for (int r = 0; r < 4; r++) lrow[r] = lrow[r] * al[r] + lt[r];
#pragma unroll
      for (int h8 = 0; h8 < 8; h8++)
#pragma unroll
        for (int r = 0; r < 4; r++) o[h8][r] *= al[r];
      // P: C-layout -> LDS (swizzled) -> A-layout; per-wave rows, DS in-order
#pragma unroll
      for (int nt = 0; nt < 4; nt++)
#pragma unroll
        for (int r = 0; r < 4; r++) {
          int prow = w * 16 + quad * 4 + r;
          int pcol = nt * 16 + ln;
          Ps[prow * 64 + (((pcol >> 3) ^ (prow & 7)) << 3) + (pcol & 7)] = f2bf(sc[nt][r]);
        }
#pragma unroll
      for (int ks2 = 0; ks2 < 2; ks2++) {
        int sw = ((ks2 * 4 + quad) ^ (ln & 7)) << 3;
        short8 pf = *(const short8*)&Ps[(w * 16 + ln) * 64 + sw];
#pragma unroll
        for (int h8 = 0; h8 < 8; h8++) {
          short8 vf = *(const short8*)&VsB[(h8 * 16 + ln) * 64 + sw];
          o[h8] = mfma16(pf, vf, o[h8]);
        }
      }
      cur ^= 1;
    }
    // epilogue: divide by l, write [B,S,H*HD] bf16
    float inv[4];
#pragma unroll
    for (int r = 0; r < 4; r++) inv[r] = 1.0f / lrow[r];
    int srow = q0 + w * 16 + quad * 4;
#pragma unroll
    for (int h8 = 0; h8 < 8; h8++) {
      int col = h8 * 16 + ln;
#pragma unroll
      for (int r = 0; r < 4; r++) {
        size_t idx = ((size_t)b * SS + srow + r) * DD + (size_t)(bh & 15) * HDIM + col;
        Out[idx] = f2bf(o[h8][r] * inv[r]);
      }
    }
  }
}

extern "C" void kernel_launch(void* const* d_in, const int* in_sizes, int n_in,
                              void* d_out, int out_size, void* d_ws, size_t ws_size,
                              hipStream_t stream) {
  const float* x    = (const float*)d_in[0];
  const int*   amask= (const int*)d_in[1];
  const float* ln1g = (const float*)d_in[2];
  const float* ln1b = (const float*)d_in[3];
  const float* wq   = (const float*)d_in[4];
  const float* bq   = (const float*)d_in[5];
  const float* wk   = (const float*)d_in[6];
  const float* bk   = (const float*)d_in[7];
  const float* wv   = (const float*)d_in[8];
  const float* bv   = (const float*)d_in[9];
  const float* wo   = (const float*)d_in[10];
  const float* bo   = (const float*)d_in[11];
  const float* ln2g = (const float*)d_in[12];
  const float* ln2b = (const float*)d_in[13];
  const float* w1   = (const float*)d_in[14];
  const float* b1   = (const float*)d_in[15];
  const float* w2   = (const float*)d_in[16];
  const float* b2   = (const float*)d_in[17];

  char* ws = (char*)d_ws;
  u16* wqT  = (u16*)(ws + 0);          // 8.39 MB each (2048x2048 bf16)
  u16* wkT  = (u16*)(ws + 8388608);    // contiguous with wqT -> fused [6144][2048]
  u16* wvT  = (u16*)(ws + 16777216);
  u16* woT  = (u16*)(ws + 25165824);
  u16* w1T  = (u16*)(ws + 33554432);   // 33.55 MB (8192x2048)
  u16* w2T  = (u16*)(ws + 67108864);   // 33.55 MB (2048x8192)
  u16* hbuf = (u16*)(ws + 100663296);  // 16.78 MB; reused for h2
  u16* qbuf = (u16*)(ws + 117440512);  // 16.78 MB  (K at +8388608 u16, Vt at +16777216 u16)
  u16* kbuf = (u16*)(ws + 134217728);
  u16* vtb  = (u16*)(ws + 150994944);
  u16* atb  = (u16*)(ws + 167772160);  // 16.78 MB
  float* x2 = (float*)(ws + 184549376);// 33.55 MB fp32
  float* kb = (float*)(ws + 218103808);// 16 KB
  u16* ff1  = qbuf;                    // overlays qbuf..atb (exactly 67.1 MB)
  // split-K partials for FFN2: overlay wqT..woT + part of w1T (both dead then).
  // 2 slices x 4096x2048 fp32 = 67.1 MB at ws+0 (w2T at +67108864 untouched).
  float* pbuf = (float*)(ws + 0);

  // weight prep (fp32 -> bf16, transposed)
  transpose_w<<<dim3(64, 64), 256, 0, stream>>>(wq, wqT, 2048, 2048);
  transpose_w<<<dim3(64, 64), 256, 0, stream>>>(wk, wkT, 2048, 2048);
  transpose_w<<<dim3(64, 64), 256, 0, stream>>>(wv, wvT, 2048, 2048);
  transpose_w<<<dim3(64, 64), 256, 0, stream>>>(wo, woT, 2048, 2048);
  transpose_w<<<dim3(256, 64), 256, 0, stream>>>(w1, w1T, 2048, 8192);
  transpose_w<<<dim3(64, 256), 256, 0, stream>>>(w2, w2T, 8192, 2048);
  prep_mask<<<16, 256, 0, stream>>>(amask, kb);

  // attention path
  ln_bf16<<<4096, 256, 0, stream>>>(x, ln1g, ln1b, hbuf);
  const float qscale = 0.08838834764831845f;  // 1/sqrt(128)
  // fused QKV: Bt = [wqT|wkT|wvT] contiguous, N=6144
  gemm_bt<4><<<dim3(48, 32), 256, 0, stream>>>(hbuf, wqT, bq, bk, bv, nullptr, qbuf,
                                               4096, 6144, 2048, qscale);
  attn_kernel<<<dim3(16, 32), 256, 0, stream>>>(qbuf, kbuf, vtb, kb, atb);
  gemm_bt<2><<<dim3(16, 32), 256, 0, stream>>>(atb, woT, bo, nullptr, nullptr, x, x2,
                                               4096, 2048, 2048, 1.0f);

  // FFN path
  ln_bf16<<<4096, 256, 0, stream>>>(x2, ln2g, ln2b, hbuf);
  gemm_bt<3><<<dim3(64, 32), 256, 0, stream>>>(hbuf, w1T, b1, nullptr, nullptr, nullptr, ff1,
                                               4096, 8192, 2048, 1.0f);
  // FFN2 via split-K=2 + 4 blocks/CU residency
  gemm_bt_splitk<<<dim3(16, 32, 2), 256, 0, stream>>>(ff1, w2T, pbuf, 4096, 2048, 8192, 4096);
  splitk_fix<<<8192, 256, 0, stream>>>(pbuf, pbuf + (size_t)4096 * 2048, b2, x2,
                                       (float*)d_out);
}

// Round 5
// 853.843 us; speedup vs baseline: 1.2121x; 1.0984x over previous
//
#include <hip/hip_runtime.h>
#include <cmath>

// Problem constants
#define BB 2
#define SS 2048
#define DD 2048
#define HH 16
#define HDIM 128
#define DFF 8192
#define MROWS 4096  // B*S

typedef unsigned short u16;
typedef unsigned int u32;
typedef short short8 __attribute__((ext_vector_type(8)));
typedef u16 u16x4 __attribute__((ext_vector_type(4)));
typedef u16 u16x8 __attribute__((ext_vector_type(8)));
typedef float f32x4 __attribute__((ext_vector_type(4)));
typedef float f4 __attribute__((ext_vector_type(4)));

__device__ __forceinline__ u16 f2bf(float f) {
  u32 u = __float_as_uint(f);
  u = (u + 0x7fffu + ((u >> 16) & 1u)) >> 16;
  return (u16)u;
}

__device__ __forceinline__ f32x4 mfma16(short8 a, short8 b, f32x4 c) {
  return __builtin_amdgcn_mfma_f32_16x16x32_bf16(a, b, c, 0, 0, 0);
}

// async global->LDS, 16B per lane. LDS dest must be wave-uniform base + lane*16,
// but the GLOBAL address is per-lane -> swizzle on the producer side.
__device__ __forceinline__ void gload16(const void* g, void* l) {
  __builtin_amdgcn_global_load_lds((const __attribute__((address_space(1))) u32*)g,
                                   (__attribute__((address_space(3))) u32*)l, 16, 0, 0);
}

// ---------------- weight transpose + bf16 convert: Wt[n][k] = bf16(W[k][n]) -----
// v2: u16x4 writes (8 B/lane) instead of 2 B/lane.
__global__ __launch_bounds__(256) void transpose_w(const float* __restrict__ W,
                                                   u16* __restrict__ Wt, int K, int N) {
  __shared__ float t[32][33];
  int n0 = blockIdx.x * 32, k0 = blockIdx.y * 32;
  int tx = threadIdx.x & 31, ty = threadIdx.x >> 5;  // ty in [0,8)
#pragma unroll
  for (int i = 0; i < 4; i++) t[ty + i * 8][tx] = W[(size_t)(k0 + ty + i * 8) * N + n0 + tx];
  __syncthreads();
  int n = threadIdx.x >> 3, kq = threadIdx.x & 7;  // 32 n x 8 k-quads
  u16x4 v;
#pragma unroll
  for (int m = 0; m < 4; m++) v[m] = f2bf(t[kq * 4 + m][n]);
  *(u16x4*)&Wt[(size_t)(n0 + n) * K + k0 + kq * 4] = v;
}

// ---------------- key-padding bias: kb[i] = mask ? 0 : -1e30 ----------------
__global__ void prep_mask(const int* __restrict__ m, float* __restrict__ kb) {
  int i = blockIdx.x * 256 + threadIdx.x;
  kb[i] = m[i] ? 0.f : -1e30f;
}

// ---------------- layernorm row kernel: fp32 in -> bf16 out ----------------
__global__ __launch_bounds__(256) void ln_bf16(const float* __restrict__ x,
                                               const float* __restrict__ g,
                                               const float* __restrict__ bta,
                                               u16* __restrict__ out) {
  int row = blockIdx.x;
  int t = threadIdx.x;
  const f4* xr = (const f4*)(x + (size_t)row * DD);
  f4 a = xr[t * 2], c = xr[t * 2 + 1];
  float s = a[0] + a[1] + a[2] + a[3] + c[0] + c[1] + c[2] + c[3];
  float q = a[0]*a[0] + a[1]*a[1] + a[2]*a[2] + a[3]*a[3]
          + c[0]*c[0] + c[1]*c[1] + c[2]*c[2] + c[3]*c[3];
#pragma unroll
  for (int off = 32; off >= 1; off >>= 1) {
    s += __shfl_down(s, off);
    q += __shfl_down(q, off);
  }
  __shared__ float red[8];
  int wv = t >> 6;
  if ((t & 63) == 0) { red[wv] = s; red[4 + wv] = q; }
  __syncthreads();
  s = red[0] + red[1] + red[2] + red[3];
  q = red[4] + red[5] + red[6] + red[7];
  float mu = s * (1.f / DD);
  float rstd = rsqrtf(q * (1.f / DD) - mu * mu + 1e-5f);
  const f4* gp = (const f4*)g;
  const f4* bp = (const f4*)bta;
  f4 g0 = gp[t * 2], g1 = gp[t * 2 + 1], b0 = bp[t * 2], b1 = bp[t * 2 + 1];
  u16x8 r8;
  r8[0] = f2bf((a[0] - mu) * rstd * g0[0] + b0[0]);
  r8[1] = f2bf((a[1] - mu) * rstd * g0[1] + b0[1]);
  r8[2] = f2bf((a[2] - mu) * rstd * g0[2] + b0[2]);
  r8[3] = f2bf((a[3] - mu) * rstd * g0[3] + b0[3]);
  r8[4] = f2bf((c[0] - mu) * rstd * g1[0] + b1[0]);
  r8[5] = f2bf((c[1] - mu) * rstd * g1[1] + b1[1]);
  r8[6] = f2bf((c[2] - mu) * rstd * g1[2] + b1[2]);
  r8[7] = f2bf((c[3] - mu) * rstd * g1[3] + b1[3]);
  *(u16x8*)(out + (size_t)row * DD + t * 8) = r8;
}

// ---------------- generic bf16 GEMM: C = A[M,K] @ Wt[N,K]^T --------------------
// BK=64 K-tile (32 MFMA per barrier pair vs 16 at BK=32), XOR-chunk-swizzled LDS
// (row stride 128B would put all 16 ln-lanes on one bank group; swizzle spreads
// them -> 8 words/bank, optimal). Two k-halves keep live regs ~116 < 128 so
// __launch_bounds__(256,4) holds 4 blocks/CU (R4: the decisive variable).
// EPI 2: out fp32 [M,N] = acc + bias + resid
// EPI 3: out bf16 [M,N] = gelu_exact(acc + bias)
// EPI 4: fused QKV: N=6144; col<2048 -> Q*scale; <4096 -> K; else V^T.
template <int EPI>
__global__ __launch_bounds__(256, 4) void gemm_bt(const u16* __restrict__ A,
                                               const u16* __restrict__ Bt,
                                               const float* __restrict__ bias,
                                               const float* __restrict__ bias2,
                                               const float* __restrict__ bias3,
                                               const float* __restrict__ resid,
                                               void* __restrict__ outp,
                                               int M, int N, int K, float scale) {
  __shared__ u16 As[128 * 64];
  __shared__ u16 Bs[128 * 64];
  int tid = threadIdx.x, w = tid >> 6, lane = tid & 63, ln = lane & 15, quad = lane >> 4;
  int n0 = blockIdx.x * 128, m0 = blockIdx.y * 128;
  int wm = (w & 1) * 64, wn = (w >> 1) * 64;
  f32x4 acc[4][4] = {};
  const u16* ap = A + (size_t)m0 * K;
  const u16* bp = Bt + (size_t)n0 * K;
  int nkt = K >> 6;
  for (int kt = 0; kt < nkt; kt++) {
    int k0 = kt * 64;
#pragma unroll
    for (int i = 0; i < 4; i++) {
      int c = i * 256 + tid, row = c >> 3, sl = c & 7;
      gload16(ap + (size_t)row * K + k0 + ((sl ^ (row & 7)) << 3), &As[c * 8]);
    }
#pragma unroll
    for (int i = 0; i < 4; i++) {
      int c = i * 256 + tid, row = c >> 3, sl = c & 7;
      gload16(bp + (size_t)row * K + k0 + ((sl ^ (row & 7)) << 3), &Bs[c * 8]);
    }
    __syncthreads();
#pragma unroll
    for (int h = 0; h < 2; h++) {
      short8 af[4], bf[4];
#pragma unroll
      for (int i = 0; i < 4; i++)
        af[i] = *(const short8*)&As[(wm + i * 16 + ln) * 64 + (((h * 4 + quad) ^ (ln & 7)) << 3)];
#pragma unroll
      for (int j = 0; j < 4; j++)
        bf[j] = *(const short8*)&Bs[(wn + j * 16 + ln) * 64 + (((h * 4 + quad) ^ (ln & 7)) << 3)];
#pragma unroll
      for (int i = 0; i < 4; i++)
#pragma unroll
        for (int j = 0; j < 4; j++) acc[i][j] = mfma16(af[i], bf[j], acc[i][j]);
    }
    __syncthreads();
  }
  // epilogue
#pragma unroll
  for (int i = 0; i < 4; i++) {
    int row = m0 + wm + i * 16 + quad * 4;
#pragma unroll
    for (int j = 0; j < 4; j++) {
      int col = n0 + wn + j * 16 + ln;
      float bvv;
      int qkv = 0, dcol = col;
      if (EPI == 4) {
        qkv = col >> 11;
        dcol = col & 2047;
        bvv = (qkv == 0 ? bias : qkv == 1 ? bias2 : bias3)[dcol];
      } else {
        bvv = bias[col];
      }
#pragma unroll
      for (int r = 0; r < 4; r++) {
        float v = acc[i][j][r] + bvv;
        int rw = row + r;
        if (EPI == 2) {
          v += resid[(size_t)rw * N + col];
          ((float*)outp)[(size_t)rw * N + col] = v;
        } else if (EPI == 3) {
          float gv = 0.5f * v * (1.0f + erff(v * 0.70710678118654752f));
          ((u16*)outp)[(size_t)rw * N + col] = f2bf(gv);
        } else {
          int b_ = rw >> 11, s_ = rw & 2047, hh = dcol >> 7, hd = dcol & 127;
          u16* o16 = (u16*)outp;
          if (qkv == 0) {
            o16[(((size_t)(b_ * HH + hh) * SS + s_) << 7) + hd] = f2bf(v * scale);
          } else if (qkv == 1) {
            o16[8388608 + (((size_t)(b_ * HH + hh) * SS + s_) << 7) + hd] = f2bf(v);
          } else {
            o16[16777216 + (((size_t)(b_ * HH + hh) * HDIM + hd) << 11) + s_] = f2bf(v);
          }
        }
      }
    }
  }
}

// ---------------- split-K GEMM: P[z] = A[:, z*klen:(z+1)*klen] @ Bt^T ----------
// Same BK=64 swizzled K-loop. Writes raw fp32 partial tile.
__global__ __launch_bounds__(256, 4) void gemm_bt_splitk(const u16* __restrict__ A,
                                                      const u16* __restrict__ Bt,
                                                      float* __restrict__ P,
                                                      int M, int N, int K, int klen) {
  __shared__ u16 As[128 * 64];
  __shared__ u16 Bs[128 * 64];
  int tid = threadIdx.x, w = tid >> 6, lane = tid & 63, ln = lane & 15, quad = lane >> 4;
  int n0 = blockIdx.x * 128, m0 = blockIdx.y * 128, z = blockIdx.z;
  int kbeg = z * klen;
  int wm = (w & 1) * 64, wn = (w >> 1) * 64;
  f32x4 acc[4][4] = {};
  const u16* ap = A + (size_t)m0 * K + kbeg;
  const u16* bp = Bt + (size_t)n0 * K + kbeg;
  float* Pz = P + (size_t)z * M * N;
  int nkt = klen >> 6;
  for (int kt = 0; kt < nkt; kt++) {
    int k0 = kt * 64;
#pragma unroll
    for (int i = 0; i < 4; i++) {
      int c = i * 256 + tid, row = c >> 3, sl = c & 7;
      gload16(ap + (size_t)row * K + k0 + ((sl ^ (row & 7)) << 3), &As[c * 8]);
    }
#pragma unroll
    for (int i = 0; i < 4; i++) {
      int c = i * 256 + tid, row = c >> 3, sl = c & 7;
      gload16(bp + (size_t)row * K + k0 + ((sl ^ (row & 7)) << 3), &Bs[c * 8]);
    }
    __syncthreads();
#pragma unroll
    for (int h = 0; h < 2; h++) {
      short8 af[4], bf[4];
#pragma unroll
      for (int i = 0; i < 4; i++)
        af[i] = *(const short8*)&As[(wm + i * 16 + ln) * 64 + (((h * 4 + quad) ^ (ln & 7)) << 3)];
#pragma unroll
      for (int j = 0; j < 4; j++)
        bf[j] = *(const short8*)&Bs[(wn + j * 16 + ln) * 64 + (((h * 4 + quad) ^ (ln & 7)) << 3)];
#pragma unroll
      for (int i = 0; i < 4; i++)
#pragma unroll
        for (int j = 0; j < 4; j++) acc[i][j] = mfma16(af[i], bf[j], acc[i][j]);
    }
    __syncthreads();
  }
#pragma unroll
  for (int i = 0; i < 4; i++) {
    int row = m0 + wm + i * 16 + quad * 4;
#pragma unroll
    for (int j = 0; j < 4; j++) {
      int col = n0 + wn + j * 16 + ln;
#pragma unroll
      for (int r = 0; r < 4; r++) Pz[(size_t)(row + r) * N + col] = acc[i][j][r];
    }
  }
}

// ---------------- split-K fixup: out = p0 + p1 + bias[col] + resid ------------
__global__ __launch_bounds__(256) void splitk_fix(const float* __restrict__ P0,
                                                  const float* __restrict__ P1,
                                                  const float* __restrict__ bias,
                                                  const float* __restrict__ resid,
                                                  float* __restrict__ out) {
  int i = blockIdx.x * 1024 + threadIdx.x * 4;
  f4 a = *(const f4*)(P0 + i);
  f4 b = *(const f4*)(P1 + i);
  f4 rr = *(const f4*)(resid + i);
  f4 bb = *(const f4*)(bias + (i & 2047));
  f4 o = a + b + rr + bb;
  *(f4*)(out + i) = o;
}

// ---------------- flash attention v2 --------------------------------------
// Q pre-scaled by 1/sqrt(HD) at QKV epilogue. Causal + key-pad bias.
// Q,K: bf16 [B*H, S, HD]; Vt: bf16 [B*H, HD, S]; out: bf16 [B, S, H*HD]
// - paired Q-tiles (qt, 31-qt): every block does exactly 33 K-tile iterations
// - XOR chunk-swizzled LDS (16B granularity) -> conflict-free b128 reads
// - double-buffered K/V staging, prefetch issued right after the top barrier
__global__ __launch_bounds__(256) void attn_kernel(const u16* __restrict__ Q,
                                                   const u16* __restrict__ Kg,
                                                   const u16* __restrict__ Vtg,
                                                   const float* __restrict__ kb,
                                                   u16* __restrict__ Out) {
  __shared__ u16 Ks[2][64 * 128];  // logical [sk][hd], chunk-swizzled
  __shared__ u16 Vs[2][128 * 64];  // logical [hd][sk], chunk-swizzled
  __shared__ u16 Ps[64 * 64];      // logical [q][sk], chunk-swizzled, per-wave rows
  int tid = threadIdx.x, w = tid >> 6, lane = tid & 63, ln = lane & 15, quad = lane >> 4;
  int bh = blockIdx.y, b = bh >> 4;
  const u16* kgB = Kg + (size_t)bh * SS * HDIM;
  const u16* vgB = Vtg + (size_t)bh * HDIM * SS;

  auto stage = [&](int buf, int kt) {
    const u16* kg = kgB + (size_t)kt * 64 * HDIM;
#pragma unroll
    for (int i = 0; i < 4; i++) {
      int c = i * 256 + tid, r = c >> 4;
      int jl = (c & 15) ^ (r & 7);
      gload16(kg + r * HDIM + jl * 8, &Ks[buf][c * 8]);
    }
    const u16* vg = vgB + kt * 64;
#pragma unroll
    for (int i = 0; i < 4; i++) {
      int c = i * 256 + tid, r = c >> 3;
      int jl = (c & 7) ^ (r & 7);
      gload16(vg + (size_t)r * SS + jl * 8, &Vs[buf][c * 8]);
    }
  };

#pragma unroll 1
  for (int half = 0; half < 2; half++) {
    int qt = half ? (31 - blockIdx.x) : blockIdx.x;
    int q0 = qt * 64;
    short8 qf[4];
    size_t qbase = ((size_t)bh * SS + q0 + w * 16 + ln) * HDIM;
#pragma unroll
    for (int ks = 0; ks < 4; ks++) qf[ks] = *(const short8*)(Q + qbase + ks * 32 + quad * 8);
    f32x4 o[8] = {};
    float mrow[4], lrow[4];
#pragma unroll
    for (int r = 0; r < 4; r++) { mrow[r] = -1e30f; lrow[r] = 0.f; }
    int nkt = qt + 1;
    __syncthreads();  // prior half's LDS reads complete before restaging
    stage(0, 0);
    int cur = 0;
    for (int kt = 0; kt < nkt; kt++) {
      __syncthreads();  // drains loads staged one iteration ago
      if (kt + 1 < nkt) stage(cur ^ 1, kt + 1);
      const u16* KsB = Ks[cur];
      const u16* VsB = Vs[cur];
      float kbv[4];
#pragma unroll
      for (int nt = 0; nt < 4; nt++) kbv[nt] = kb[b * SS + kt * 64 + nt * 16 + ln];
      // S = Q K^T
      f32x4 sc[4] = {};
#pragma unroll
      for (int ks = 0; ks < 4; ks++)
#pragma unroll
        for (int nt = 0; nt < 4; nt++) {
          short8 kf = *(const short8*)&KsB[(nt * 16 + ln) * 128 +
                                           (((ks * 4 + quad) ^ (ln & 7)) << 3)];
          sc[nt] = mfma16(qf[ks], kf, sc[nt]);
        }
      // online softmax
      bool diag = (kt == nkt - 1);
      int rowg = q0 + w * 16 + quad * 4;
      float mt[4] = {-3e30f, -3e30f, -3e30f, -3e30f};
#pragma unroll
      for (int nt = 0; nt < 4; nt++) {
        int colg = kt * 64 + nt * 16 + ln;
#pragma unroll
        for (int r = 0; r < 4; r++) {
          float s = sc[nt][r] + kbv[nt];
          if (diag && colg > rowg + r) s = -3e30f;
          sc[nt][r] = s;
          mt[r] = fmaxf(mt[r], s);
        }
      }
#pragma unroll
      for (int off = 8; off >= 1; off >>= 1)
#pragma unroll
        for (int r = 0; r < 4; r++) mt[r] = fmaxf(mt[r], __shfl_xor(mt[r], off, 16));
      float al[4], lt[4];
#pragma unroll
      for (int r = 0; r < 4; r++) {
        float mn = fmaxf(mrow[r], mt[r]);
        al[r] = __expf(mrow[r] - mn);
        mrow[r] = mn;
        lt[r] = 0.f;
      }
#pragma unroll
      for (int nt = 0; nt < 4; nt++)
#pragma unroll
        for (int r = 0; r < 4; r++) {
          float e = __expf(sc[nt][r] - mrow[r]);
          sc[nt][r] = e;
          lt[r] += e;
        }
#pragma unroll
      for (int off = 8; off >= 1; off >>= 1)
#pragma unroll
        for (int r = 0; r < 4; r++) lt[r] += __shfl_xor(lt[r], off, 16);
#pragma unroll
      for (int r = 0; r < 4; r++) lrow[r] = lrow[r] * al[r] + lt[r];
#pragma unroll
      for (int h8 = 0; h8 < 8; h8++)
#pragma unroll
        for (int r = 0; r < 4; r++) o[h8][r] *= al[r];
      // P: C-layout -> LDS (swizzled) -> A-layout; per-wave rows, DS in-order
#pragma unroll
      for (int nt = 0; nt < 4; nt++)
#pragma unroll
        for (int r = 0; r < 4; r++) {
          int prow = w * 16 + quad * 4 + r;
          int pcol = nt * 16 + ln;
          Ps[prow * 64 + (((pcol >> 3) ^ (prow & 7)) << 3) + (pcol & 7)] = f2bf(sc[nt][r]);
        }
#pragma unroll
      for (int ks2 = 0; ks2 < 2; ks2++) {
        int sw = ((ks2 * 4 + quad) ^ (ln & 7)) << 3;
        short8 pf = *(const short8*)&Ps[(w * 16 + ln) * 64 + sw];
#pragma unroll
        for (int h8 = 0; h8 < 8; h8++) {
          short8 vf = *(const short8*)&VsB[(h8 * 16 + ln) * 64 + sw];
          o[h8] = mfma16(pf, vf, o[h8]);
        }
      }
      cur ^= 1;
    }
    // epilogue: divide by l, write [B,S,H*HD] bf16
    float inv[4];
#pragma unroll
    for (int r = 0; r < 4; r++) inv[r] = 1.0f / lrow[r];
    int srow = q0 + w * 16 + quad * 4;
#pragma unroll
    for (int h8 = 0; h8 < 8; h8++) {
      int col = h8 * 16 + ln;
#pragma unroll
      for (int r = 0; r < 4; r++) {
        size_t idx = ((size_t)b * SS + srow + r) * DD + (size_t)(bh & 15) * HDIM + col;
        Out[idx] = f2bf(o[h8][r] * inv[r]);
      }
    }
  }
}

extern "C" void kernel_launch(void* const* d_in, const int* in_sizes, int n_in,
                              void* d_out, int out_size, void* d_ws, size_t ws_size,
                              hipStream_t stream) {
  const float* x    = (const float*)d_in[0];
  const int*   amask= (const int*)d_in[1];
  const float* ln1g = (const float*)d_in[2];
  const float* ln1b = (const float*)d_in[3];
  const float* wq   = (const float*)d_in[4];
  const float* bq   = (const float*)d_in[5];
  const float* wk   = (const float*)d_in[6];
  const float* bk   = (const float*)d_in[7];
  const float* wv   = (const float*)d_in[8];
  const float* bv   = (const float*)d_in[9];
  const float* wo   = (const float*)d_in[10];
  const float* bo   = (const float*)d_in[11];
  const float* ln2g = (const float*)d_in[12];
  const float* ln2b = (const float*)d_in[13];
  const float* w1   = (const float*)d_in[14];
  const float* b1   = (const float*)d_in[15];
  const float* w2   = (const float*)d_in[16];
  const float* b2   = (const float*)d_in[17];

  char* ws = (char*)d_ws;
  u16* wqT  = (u16*)(ws + 0);          // 8.39 MB each (2048x2048 bf16)
  u16* wkT  = (u16*)(ws + 8388608);    // contiguous with wqT -> fused [6144][2048]
  u16* wvT  = (u16*)(ws + 16777216);
  u16* woT  = (u16*)(ws + 25165824);
  u16* w1T  = (u16*)(ws + 33554432);   // 33.55 MB (8192x2048)
  u16* w2T  = (u16*)(ws + 67108864);   // 33.55 MB (2048x8192)
  u16* hbuf = (u16*)(ws + 100663296);  // 16.78 MB; reused for h2
  u16* qbuf = (u16*)(ws + 117440512);  // 16.78 MB  (K at +8388608 u16, Vt at +16777216 u16)
  u16* kbuf = (u16*)(ws + 134217728);
  u16* vtb  = (u16*)(ws + 150994944);
  u16* atb  = (u16*)(ws + 167772160);  // 16.78 MB
  float* x2 = (float*)(ws + 184549376);// 33.55 MB fp32
  float* kb = (float*)(ws + 218103808);// 16 KB
  u16* ff1  = qbuf;                    // overlays qbuf..atb (exactly 67.1 MB)
  // split-K partials for FFN2: overlay wqT..woT + part of w1T (both dead then).
  float* pbuf = (float*)(ws + 0);

  // weight prep (fp32 -> bf16, transposed)
  transpose_w<<<dim3(64, 64), 256, 0, stream>>>(wq, wqT, 2048, 2048);
  transpose_w<<<dim3(64, 64), 256, 0, stream>>>(wk, wkT, 2048, 2048);
  transpose_w<<<dim3(64, 64), 256, 0, stream>>>(wv, wvT, 2048, 2048);
  transpose_w<<<dim3(64, 64), 256, 0, stream>>>(wo, woT, 2048, 2048);
  transpose_w<<<dim3(256, 64), 256, 0, stream>>>(w1, w1T, 2048, 8192);
  transpose_w<<<dim3(64, 256), 256, 0, stream>>>(w2, w2T, 8192, 2048);
  prep_mask<<<16, 256, 0, stream>>>(amask, kb);

  // attention path
  ln_bf16<<<4096, 256, 0, stream>>>(x, ln1g, ln1b, hbuf);
  const float qscale = 0.08838834764831845f;  // 1/sqrt(128)
  // fused QKV: Bt = [wqT|wkT|wvT] contiguous, N=6144
  gemm_bt<4><<<dim3(48, 32), 256, 0, stream>>>(hbuf, wqT, bq, bk, bv, nullptr, qbuf,
                                               4096, 6144, 2048, qscale);
  attn_kernel<<<dim3(16, 32), 256, 0, stream>>>(qbuf, kbuf, vtb, kb, atb);
  gemm_bt<2><<<dim3(16, 32), 256, 0, stream>>>(atb, woT, bo, nullptr, nullptr, x, x2,
                                               4096, 2048, 2048, 1.0f);

  // FFN path
  ln_bf16<<<4096, 256, 0, stream>>>(x2, ln2g, ln2b, hbuf);
  gemm_bt<3><<<dim3(64, 32), 256, 0, stream>>>(hbuf, w1T, b1, nullptr, nullptr, nullptr, ff1,
                                               4096, 8192, 2048, 1.0f);
  // FFN2 via split-K=2 + 4 blocks/CU residency
  gemm_bt_splitk<<<dim3(16, 32, 2), 256, 0, stream>>>(ff1, w2T, pbuf, 4096, 2048, 8192, 4096);
  splitk_fix<<<8192, 256, 0, stream>>>(pbuf, pbuf + (size_t)4096 * 2048, b2, x2,
                                       (float*)d_out);
}